// Round 7
// baseline (2396.865 us; speedup 1.0000x reference)
//
#include <hip/hip_runtime.h>

#define B_ 256
#define T_ 1024
#define H_ 64

typedef float f32x2 __attribute__((ext_vector_type(2)));
typedef float f32x4 __attribute__((ext_vector_type(4)));

// fast sigmoid/tanh via v_exp_f32 + v_rcp_f32 (validated R2-R6: absmax 0.0)
__device__ __forceinline__ float fast_sigmoid(float x) {
    float e = __builtin_amdgcn_exp2f(-1.4426950408889634f * x);
    return __builtin_amdgcn_rcpf(1.0f + e);
}
__device__ __forceinline__ float fast_tanh(float x) {
    float e = __builtin_amdgcn_exp2f(2.8853900817779268f * x);
    return 1.0f - 2.0f * __builtin_amdgcn_rcpf(1.0f + e);
}

// butterfly add via DPP: 0xB1=xor1, 0x4E=xor2, 0x141=half-mirror (=xor4 after 1,2)
template<int CTRL>
__device__ __forceinline__ float dpp_addf(float v) {
    int vi = __builtin_bit_cast(int, v);
    int sh = __builtin_amdgcn_update_dpp(0, vi, CTRL, 0xF, 0xF, true);
    return v + __builtin_bit_cast(float, sh);
}

__device__ __forceinline__ f32x2 lo4(f32x4 v) { return __builtin_shufflevector(v, v, 0, 1); }
__device__ __forceinline__ f32x2 hi4(f32x4 v) { return __builtin_shufflevector(v, v, 2, 3); }

// R7: packed fp32 math forced via inline asm (theory: compiler emitted scalar
// v_fma_f32 for elementwise_fma in R4-R6; VALUBusy arithmetic matches 2x issue).
__device__ __forceinline__ void pk_fma(f32x2& d, f32x2 a, f32x2 b) {
    asm("v_pk_fma_f32 %0, %1, %2, %0" : "+v"(d) : "v"(a), "v"(b));
}
__device__ __forceinline__ f32x2 pk_add(f32x2 a, f32x2 b) {
    f32x2 d;
    asm("v_pk_add_f32 %0, %1, %2" : "=v"(d) : "v"(a), "v"(b));
    return d;
}

// 4 gate rows x 16 k dot via v_pk_fma_f32 (same math/order class as R6, packed)
__device__ __forceinline__ void dot4x16(const f32x2 wt[4][8],
                                        f32x4 h0, f32x4 h1, f32x4 h2, f32x4 h3,
                                        float acc[4]) {
    f32x2 e0 = lo4(h0), o0 = hi4(h0), e1 = lo4(h1), o1 = hi4(h1);
    f32x2 e2 = lo4(h2), o2 = hi4(h2), e3 = lo4(h3), o3 = hi4(h3);
    #pragma unroll
    for (int r = 0; r < 4; ++r) {
        f32x2 a = {0.f, 0.f}, d = {0.f, 0.f};
        pk_fma(a, wt[r][0], e0); pk_fma(d, wt[r][1], o0);
        pk_fma(a, wt[r][2], e1); pk_fma(d, wt[r][3], o1);
        pk_fma(a, wt[r][4], e2); pk_fma(d, wt[r][5], o2);
        pk_fma(a, wt[r][6], e3); pk_fma(d, wt[r][7], o3);
        f32x2 s = pk_add(a, d);
        acc[r] = s.x + s.y;
    }
}

// load one weight row-chunk (16 floats) as 8 pinned f32x2
__device__ __forceinline__ void load_row16(const float* base, f32x2 wt[8]) {
    #pragma unroll
    for (int q = 0; q < 4; ++q) {
        f32x4 w4 = *(const f32x4*)(base + 4 * q);
        wt[2 * q]     = lo4(w4);
        wt[2 * q + 1] = hi4(w4);
    }
}

// ---------------------------------------------------------------------------
// Diagonal pair (R6-validated structure): layer A computes t=s, layer B t=s-1.
// A's h -> LDS only (B's x-slot); B's h -> global. 80B-padded chunks, DPP
// reduce, in-place activation on kc==0 lanes, asm-pinned weights.
// ---------------------------------------------------------------------------
template<bool A_L0>
__global__ __attribute__((amdgpu_flat_work_group_size(A_L0 ? 768 : 1024,
                                                      A_L0 ? 768 : 1024)))
void lstm_pair(const float* xA,                    // L0: [B,T]; else [B,T,64] (may alias hB_out)
               float* __restrict__ hB_out,         // [B,T,64]
               const float* __restrict__ wA_ih,    // L0: [256]; else [256,64]
               const float* __restrict__ wA_hh,    // [256,64]
               const float* __restrict__ bA_ih,    // [256]
               const float* __restrict__ bA_hh,    // [256]
               const float* __restrict__ wB_ih,    // [256,64]
               const float* __restrict__ wB_hh,    // [256,64]
               const float* __restrict__ bB_ih,    // [256]
               const float* __restrict__ bB_hh)    // [256]
{
    const int b   = blockIdx.x;
    const int tid = threadIdx.x;
    const bool isB = (tid < 512);

    __shared__ __align__(16) float xhA[2][A_L0 ? 80 : 160];  // A: [x|]h chunks, padded
    __shared__ __align__(16) float xhB[2][160];              // B: [h_A | h_B] chunks

    // ---------------- per-role setup ----------------
    int kc, j;
    f32x2 wt[4][8];
    float bias0 = 0.f, bias1 = 0.f, bias2 = 0.f, bias3 = 0.f;
    float w00 = 0.f, w01 = 0.f, w02 = 0.f, w03 = 0.f;   // L0 scalar-x weights

    if (isB) {
        kc = tid & 7; j = tid >> 3;
        #pragma unroll
        for (int r = 0; r < 4; ++r) {
            const int row = r * H_ + j;
            const float* base = (kc < 4) ? (wB_ih + row * H_ + kc * 16)
                                         : (wB_hh + row * H_ + (kc - 4) * 16);
            load_row16(base, wt[r]);
        }
        if (kc == 0) {
            bias0 = bB_ih[0*H_+j] + bB_hh[0*H_+j];
            bias1 = bB_ih[1*H_+j] + bB_hh[1*H_+j];
            bias2 = bB_ih[2*H_+j] + bB_hh[2*H_+j];
            bias3 = bB_ih[3*H_+j] + bB_hh[3*H_+j];
        }
    } else {
        const int t2 = tid - 512;
        if (A_L0) { kc = t2 & 3; j = t2 >> 2; }
        else      { kc = t2 & 7; j = t2 >> 3; }
        #pragma unroll
        for (int r = 0; r < 4; ++r) {
            const int row = r * H_ + j;
            const float* base;
            if (A_L0)         base = wA_hh + row * H_ + kc * 16;
            else if (kc < 4)  base = wA_ih + row * H_ + kc * 16;
            else              base = wA_hh + row * H_ + (kc - 4) * 16;
            load_row16(base, wt[r]);
        }
        if (kc == 0) {
            bias0 = bA_ih[0*H_+j] + bA_hh[0*H_+j];
            bias1 = bA_ih[1*H_+j] + bA_hh[1*H_+j];
            bias2 = bA_ih[2*H_+j] + bA_hh[2*H_+j];
            bias3 = bA_ih[3*H_+j] + bA_hh[3*H_+j];
            if (A_L0) {
                w00 = wA_ih[0*H_+j]; w01 = wA_ih[1*H_+j];
                w02 = wA_ih[2*H_+j]; w03 = wA_ih[3*H_+j];
            }
        }
    }
    #pragma unroll
    for (int r = 0; r < 4; ++r)
        #pragma unroll
        for (int q = 0; q < 8; ++q)
            asm volatile("" : "+v"(wt[r][q]));

    float c_st = 0.f;
    float xt = (!isB && A_L0) ? xA[(long)b * T_] : 0.f;

    // ---------------- LDS init ----------------
    if (isB) {
        if (tid < H_) xhB[1][80 + (tid >> 4) * 20 + (tid & 15)] = 0.f;  // h_B[-1]=0
    } else {
        const int t2 = tid - 512;
        if (t2 < H_) {
            const int off = (t2 >> 4) * 20 + (t2 & 15);
            if (A_L0) {
                xhA[0][off] = 0.f;                                   // h_A[-1]=0
            } else {
                xhA[0][off]      = xA[((long)b * T_) * H_ + t2];     // x row 0
                xhA[0][80 + off] = 0.f;                              // h_A[-1]=0
            }
        }
    }
    __syncthreads();

    // ---------------- diagonal steps ----------------
    for (int s = 0; s <= T_; ++s) {
        const int rb = s & 1, wb = rb ^ 1;

        if (isB) {
            if (s >= 1) {
                const f32x4* xv = (const f32x4*)&xhB[rb][kc * 20];
                f32x4 h0 = xv[0], h1 = xv[1], h2 = xv[2], h3 = xv[3];
                float acc[4];
                dot4x16(wt, h0, h1, h2, h3, acc);
                acc[0] = dpp_addf<0xB1>(acc[0]); acc[1] = dpp_addf<0xB1>(acc[1]);
                acc[2] = dpp_addf<0xB1>(acc[2]); acc[3] = dpp_addf<0xB1>(acc[3]);
                acc[0] = dpp_addf<0x4E>(acc[0]); acc[1] = dpp_addf<0x4E>(acc[1]);
                acc[2] = dpp_addf<0x4E>(acc[2]); acc[3] = dpp_addf<0x4E>(acc[3]);
                acc[0] = dpp_addf<0x141>(acc[0]); acc[1] = dpp_addf<0x141>(acc[1]);
                acc[2] = dpp_addf<0x141>(acc[2]); acc[3] = dpp_addf<0x141>(acc[3]);
                if (kc == 0) {
                    float i_ = fast_sigmoid(acc[0] + bias0);
                    float f_ = fast_sigmoid(acc[1] + bias1);
                    float g_ = fast_tanh   (acc[2] + bias2);
                    float o_ = fast_sigmoid(acc[3] + bias3);
                    c_st = f_ * c_st + i_ * g_;
                    float h = o_ * fast_tanh(c_st);
                    xhB[wb][80 + (j >> 4) * 20 + (j & 15)] = h;
                    hB_out[((long)b * T_ + (s - 1)) * H_ + j] = h;
                }
            }
        } else {
            if (s < T_) {
                float xn = 0.f;
                if (A_L0) {
                    if (s + 1 < T_) xn = xA[(long)b * T_ + s + 1];   // uniform
                } else {
                    if (kc == 1 && s + 1 < T_)
                        xn = xA[((long)b * T_ + s + 1) * H_ + j];
                }
                const f32x4* xv = (const f32x4*)&xhA[rb][kc * 20];
                f32x4 h0 = xv[0], h1 = xv[1], h2 = xv[2], h3 = xv[3];
                float acc[4];
                dot4x16(wt, h0, h1, h2, h3, acc);
                acc[0] = dpp_addf<0xB1>(acc[0]); acc[1] = dpp_addf<0xB1>(acc[1]);
                acc[2] = dpp_addf<0xB1>(acc[2]); acc[3] = dpp_addf<0xB1>(acc[3]);
                acc[0] = dpp_addf<0x4E>(acc[0]); acc[1] = dpp_addf<0x4E>(acc[1]);
                acc[2] = dpp_addf<0x4E>(acc[2]); acc[3] = dpp_addf<0x4E>(acc[3]);
                if constexpr (!A_L0) {
                    acc[0] = dpp_addf<0x141>(acc[0]); acc[1] = dpp_addf<0x141>(acc[1]);
                    acc[2] = dpp_addf<0x141>(acc[2]); acc[3] = dpp_addf<0x141>(acc[3]);
                }
                if (kc == 0) {
                    float gi = acc[0] + bias0, gf = acc[1] + bias1;
                    float gg = acc[2] + bias2, go = acc[3] + bias3;
                    if constexpr (A_L0) {
                        gi += w00 * xt; gf += w01 * xt; gg += w02 * xt; go += w03 * xt;
                    }
                    float i_ = fast_sigmoid(gi);
                    float f_ = fast_sigmoid(gf);
                    float g_ = fast_tanh(gg);
                    float o_ = fast_sigmoid(go);
                    c_st = f_ * c_st + i_ * g_;
                    float h = o_ * fast_tanh(c_st);
                    const int off = (j >> 4) * 20 + (j & 15);
                    if constexpr (A_L0) xhA[wb][off] = h;
                    else                xhA[wb][80 + off] = h;
                    xhB[wb][off] = h;                      // feed B's x-slot
                }
                if constexpr (!A_L0) {
                    if (kc == 1) xhA[wb][(j >> 4) * 20 + (j & 15)] = xn;
                }
                if constexpr (A_L0) xt = xn;
            }
        }
        __syncthreads();
    }
}

// ---------------------------------------------------------------------------
// Single layer (R4/R6-validated structure, pk math): used for L4.
// ---------------------------------------------------------------------------
template<bool L0>
__global__ __attribute__((amdgpu_flat_work_group_size(L0 ? 256 : 512, L0 ? 256 : 512),
                          amdgpu_waves_per_eu(2)))
void lstm_layer_v4(const float* x_in,
                   float* h_out,
                   const float* __restrict__ w_ih,
                   const float* __restrict__ w_hh,
                   const float* __restrict__ b_ih,
                   const float* __restrict__ b_hh)
{
    constexpr int NCH = L0 ? 4 : 8;
    const int b   = blockIdx.x;
    const int tid = threadIdx.x;
    const int kc  = tid & (NCH - 1);
    const int j   = tid >> (L0 ? 2 : 3);

    __shared__ __align__(16) float xh[2][NCH * 20];

    f32x2 wt[4][8];
    #pragma unroll
    for (int r = 0; r < 4; ++r) {
        const int row = r * H_ + j;
        const float* base;
        if (L0)           base = w_hh + row * H_ + kc * 16;
        else if (kc < 4)  base = w_ih + row * H_ + kc * 16;
        else              base = w_hh + row * H_ + (kc - 4) * 16;
        load_row16(base, wt[r]);
    }
    #pragma unroll
    for (int r = 0; r < 4; ++r)
        #pragma unroll
        for (int q = 0; q < 8; ++q)
            asm volatile("" : "+v"(wt[r][q]));

    float bias0 = 0.f, bias1 = 0.f, bias2 = 0.f, bias3 = 0.f;
    float w00 = 0.f, w01 = 0.f, w02 = 0.f, w03 = 0.f;
    if (kc == 0) {
        bias0 = b_ih[0*H_+j] + b_hh[0*H_+j];
        bias1 = b_ih[1*H_+j] + b_hh[1*H_+j];
        bias2 = b_ih[2*H_+j] + b_hh[2*H_+j];
        bias3 = b_ih[3*H_+j] + b_hh[3*H_+j];
        if (L0) {
            w00 = w_ih[0*H_+j]; w01 = w_ih[1*H_+j];
            w02 = w_ih[2*H_+j]; w03 = w_ih[3*H_+j];
        }
    }
    float c_st = 0.f;
    float xt = L0 ? x_in[(long)b * T_] : 0.f;

    if (tid < H_) {
        if (L0) {
            xh[0][(tid >> 4) * 20 + (tid & 15)] = 0.f;
        } else {
            xh[0][(tid >> 4) * 20 + (tid & 15)] = x_in[((long)b * T_) * H_ + tid];
            xh[0][80 + (tid >> 4) * 20 + (tid & 15)] = 0.f;
        }
    }
    __syncthreads();

    for (int t = 0; t < T_; ++t) {
        const int rb = t & 1, wb = rb ^ 1;

        float xn = 0.f;
        if (L0) {
            if (t + 1 < T_) xn = x_in[(long)b * T_ + t + 1];
        } else {
            if (kc == 1 && t + 1 < T_)
                xn = x_in[((long)b * T_ + t + 1) * H_ + j];
        }

        const f32x4* xv = (const f32x4*)&xh[rb][kc * 20];
        f32x4 h0 = xv[0], h1 = xv[1], h2 = xv[2], h3 = xv[3];
        float acc[4];
        dot4x16(wt, h0, h1, h2, h3, acc);

        acc[0] = dpp_addf<0xB1>(acc[0]); acc[1] = dpp_addf<0xB1>(acc[1]);
        acc[2] = dpp_addf<0xB1>(acc[2]); acc[3] = dpp_addf<0xB1>(acc[3]);
        acc[0] = dpp_addf<0x4E>(acc[0]); acc[1] = dpp_addf<0x4E>(acc[1]);
        acc[2] = dpp_addf<0x4E>(acc[2]); acc[3] = dpp_addf<0x4E>(acc[3]);
        if constexpr (!L0) {
            acc[0] = dpp_addf<0x141>(acc[0]); acc[1] = dpp_addf<0x141>(acc[1]);
            acc[2] = dpp_addf<0x141>(acc[2]); acc[3] = dpp_addf<0x141>(acc[3]);
        }

        if (kc == 0) {
            float gi = acc[0] + bias0, gf = acc[1] + bias1;
            float gg = acc[2] + bias2, go = acc[3] + bias3;
            if constexpr (L0) {
                gi += w00 * xt; gf += w01 * xt; gg += w02 * xt; go += w03 * xt;
            }
            float i_ = fast_sigmoid(gi);
            float f_ = fast_sigmoid(gf);
            float g_ = fast_tanh(gg);
            float o_ = fast_sigmoid(go);
            c_st = f_ * c_st + i_ * g_;
            float h = o_ * fast_tanh(c_st);
            if constexpr (L0) xh[wb][(j >> 4) * 20 + (j & 15)] = h;
            else              xh[wb][80 + (j >> 4) * 20 + (j & 15)] = h;
            h_out[((long)b * T_ + t) * H_ + j] = h;
        }
        if constexpr (!L0) {
            if (kc == 1) xh[wb][(j >> 4) * 20 + (j & 15)] = xn;
        }
        __syncthreads();
        if constexpr (L0) xt = xn;
    }
}

// MLP head (R3-R6-validated): wave-uniform W1 -> scalar loads. 25 us, not hot.
__global__ __launch_bounds__(256)
void mlp_head_v2(const float* __restrict__ hbuf,
                 const float* __restrict__ W1,
                 const float* __restrict__ b1,
                 const float* __restrict__ W2,
                 const float* __restrict__ b2,
                 float* __restrict__ out)
{
    const long r = (long)blockIdx.x * 256 + threadIdx.x;

    float row[H_];
    const float4* src = (const float4*)(hbuf + r * H_);
    #pragma unroll
    for (int q = 0; q < 16; ++q) {
        float4 v = src[q];
        row[4*q+0] = fmaxf(v.x, 0.f); row[4*q+1] = fmaxf(v.y, 0.f);
        row[4*q+2] = fmaxf(v.z, 0.f); row[4*q+3] = fmaxf(v.w, 0.f);
    }
    #pragma unroll
    for (int q = 0; q < 16; ++q)
        asm volatile("" : "+v"(row[4*q]), "+v"(row[4*q+1]),
                         "+v"(row[4*q+2]), "+v"(row[4*q+3]));

    float acc = b2[0];
    for (int jj = 0; jj < H_; ++jj) {
        const float* wrow = W1 + jj * H_;
        float s0 = 0.f, s1 = 0.f, s2 = 0.f, s3 = 0.f;
        #pragma unroll
        for (int q = 0; q < 16; ++q) {
            s0 += row[4*q+0] * wrow[4*q+0];
            s1 += row[4*q+1] * wrow[4*q+1];
            s2 += row[4*q+2] * wrow[4*q+2];
            s3 += row[4*q+3] * wrow[4*q+3];
        }
        float y = fmaxf(b1[jj] + (s0 + s1) + (s2 + s3), 0.f);
        acc += y * W2[jj];
    }
    out[r] = acc;
}

extern "C" void kernel_launch(void* const* d_in, const int* in_sizes, int n_in,
                              void* d_out, int out_size, void* d_ws, size_t ws_size,
                              hipStream_t stream) {
    const float* x     = (const float*)d_in[0];   // [B,T,1]
    const float* w_ih0 = (const float*)d_in[1];   // [256]
    const float* w_ihr = (const float*)d_in[2];   // [4,256,64]
    const float* w_hh  = (const float*)d_in[3];   // [5,256,64]
    const float* b_ih  = (const float*)d_in[4];   // [5,256]
    const float* b_hh  = (const float*)d_in[5];   // [5,256]
    const float* W1    = (const float*)d_in[6];   // [64,64]
    const float* b1    = (const float*)d_in[7];   // [64]
    const float* W2    = (const float*)d_in[8];   // [64]
    const float* b2    = (const float*)d_in[9];   // [1]
    // d_in[10] = future (0)

    float* out = (float*)d_out;
    float* buf = (float*)d_ws;                    // [B,T,64] fp32 = 64 MB

    const long LW = 4L * H_ * H_;   // 16384 floats per layer weight block
    const long LB = 4L * H_;        // 256 floats per layer bias block

    // K1: [L0 + L1] diagonal pair -> buf = h_L1
    lstm_pair<true><<<dim3(B_), dim3(768), 0, stream>>>(
        x, buf,
        w_ih0,            w_hh + 0 * LW, b_ih + 0 * LB, b_hh + 0 * LB,
        w_ihr + 0 * LW,   w_hh + 1 * LW, b_ih + 1 * LB, b_hh + 1 * LB);

    // K2: [L2 + L3] diagonal pair, in-place on buf -> buf = h_L3
    lstm_pair<false><<<dim3(B_), dim3(1024), 0, stream>>>(
        buf, buf,
        w_ihr + 1 * LW,   w_hh + 2 * LW, b_ih + 2 * LB, b_hh + 2 * LB,
        w_ihr + 2 * LW,   w_hh + 3 * LW, b_ih + 3 * LB, b_hh + 3 * LB);

    // K3: L4 single, in-place -> buf = h_L4
    lstm_layer_v4<false><<<dim3(B_), dim3(512), 0, stream>>>(
        buf, buf,
        w_ihr + 3 * LW,   w_hh + 4 * LW, b_ih + 4 * LB, b_hh + 4 * LB);

    mlp_head_v2<<<dim3((B_ * T_) / 256), dim3(256), 0, stream>>>(
        buf, W1, b1, W2, b2, out);
}

// Round 8
// 1751.753 us; speedup vs baseline: 1.3683x; 1.3683x over previous
//
#include <hip/hip_runtime.h>

#define B_ 256
#define T_ 1024
#define H_ 64

typedef float f32x2 __attribute__((ext_vector_type(2)));
typedef float f32x4 __attribute__((ext_vector_type(4)));

// fast sigmoid/tanh via v_exp_f32 + v_rcp_f32 (validated R2-R7: absmax 0.0)
__device__ __forceinline__ float fast_sigmoid(float x) {
    float e = __builtin_amdgcn_exp2f(-1.4426950408889634f * x);
    return __builtin_amdgcn_rcpf(1.0f + e);
}
__device__ __forceinline__ float fast_tanh(float x) {
    float e = __builtin_amdgcn_exp2f(2.8853900817779268f * x);
    return 1.0f - 2.0f * __builtin_amdgcn_rcpf(1.0f + e);
}

// butterfly add via DPP: 0xB1=xor1, 0x4E=xor2, 0x141=half-mirror (=xor4 after 1,2)
template<int CTRL>
__device__ __forceinline__ float dpp_addf(float v) {
    int vi = __builtin_bit_cast(int, v);
    int sh = __builtin_amdgcn_update_dpp(0, vi, CTRL, 0xF, 0xF, true);
    return v + __builtin_bit_cast(float, sh);
}

__device__ __forceinline__ f32x2 lo4(f32x4 v) { return __builtin_shufflevector(v, v, 0, 1); }
__device__ __forceinline__ f32x2 hi4(f32x4 v) { return __builtin_shufflevector(v, v, 2, 3); }

// R8: barrier that drains LDS only (no vmcnt(0)): global stores/prefetches are
// ordered by their consumers' own waitcnts; in-place buf read precedes the
// overwrite by 3 barrier rounds.
__device__ __forceinline__ void block_sync_lds() {
    asm volatile("s_waitcnt lgkmcnt(0)\n\ts_barrier" ::: "memory");
}

__device__ __forceinline__ float hsum4(f32x4 v) {
    return (v.x + v.y) + (v.z + v.w);
}

// R6-validated dot: 4 gate rows x 16 k (elementwise fma; pk is rate-neutral per R7)
__device__ __forceinline__ void dot4x16(const f32x4 wt[4][4],
                                        f32x4 h0, f32x4 h1, f32x4 h2, f32x4 h3,
                                        float acc[4]) {
    #pragma unroll
    for (int r = 0; r < 4; ++r) {
        f32x2 a = {0.f, 0.f}, d = {0.f, 0.f};
        a = __builtin_elementwise_fma(lo4(wt[r][0]), lo4(h0), a);
        d = __builtin_elementwise_fma(hi4(wt[r][0]), hi4(h0), d);
        a = __builtin_elementwise_fma(lo4(wt[r][1]), lo4(h1), a);
        d = __builtin_elementwise_fma(hi4(wt[r][1]), hi4(h1), d);
        a = __builtin_elementwise_fma(lo4(wt[r][2]), lo4(h2), a);
        d = __builtin_elementwise_fma(hi4(wt[r][2]), hi4(h2), d);
        a = __builtin_elementwise_fma(lo4(wt[r][3]), lo4(h3), a);
        d = __builtin_elementwise_fma(hi4(wt[r][3]), hi4(h3), d);
        f32x2 s = a + d;
        acc[r] = s.x + s.y;
    }
}

// ---------------------------------------------------------------------------
// K1: diagonal pair [L0+L1] (R6-validated structure + relaxed barrier).
// ---------------------------------------------------------------------------
__global__ __attribute__((amdgpu_flat_work_group_size(768, 768)))
void lstm_pair01(const float* __restrict__ xA,     // [B,T] scalar input
                 float* __restrict__ hB_out,       // [B,T,64] = h_L1
                 const float* __restrict__ wA_ih,  // [256]
                 const float* __restrict__ wA_hh,  // [256,64]
                 const float* __restrict__ bA_ih,
                 const float* __restrict__ bA_hh,
                 const float* __restrict__ wB_ih,  // [256,64]
                 const float* __restrict__ wB_hh,  // [256,64]
                 const float* __restrict__ bB_ih,
                 const float* __restrict__ bB_hh)
{
    const int b   = blockIdx.x;
    const int tid = threadIdx.x;
    const bool isB = (tid < 512);

    __shared__ __align__(16) float xhA[2][80];    // A: h chunks (4x16 padded to 20)
    __shared__ __align__(16) float xhB[2][160];   // B: [h_A | h_B] chunks

    int kc, j;
    f32x4 wt[4][4];
    float bias0 = 0.f, bias1 = 0.f, bias2 = 0.f, bias3 = 0.f;
    float w00 = 0.f, w01 = 0.f, w02 = 0.f, w03 = 0.f;

    if (isB) {
        kc = tid & 7; j = tid >> 3;
        #pragma unroll
        for (int r = 0; r < 4; ++r) {
            const int row = r * H_ + j;
            const float* base = (kc < 4) ? (wB_ih + row * H_ + kc * 16)
                                         : (wB_hh + row * H_ + (kc - 4) * 16);
            #pragma unroll
            for (int q = 0; q < 4; ++q) wt[r][q] = *(const f32x4*)(base + 4 * q);
        }
        if (kc == 0) {
            bias0 = bB_ih[0*H_+j] + bB_hh[0*H_+j];
            bias1 = bB_ih[1*H_+j] + bB_hh[1*H_+j];
            bias2 = bB_ih[2*H_+j] + bB_hh[2*H_+j];
            bias3 = bB_ih[3*H_+j] + bB_hh[3*H_+j];
        }
    } else {
        const int t2 = tid - 512;
        kc = t2 & 3; j = t2 >> 2;
        #pragma unroll
        for (int r = 0; r < 4; ++r) {
            const int row = r * H_ + j;
            const float* base = wA_hh + row * H_ + kc * 16;
            #pragma unroll
            for (int q = 0; q < 4; ++q) wt[r][q] = *(const f32x4*)(base + 4 * q);
        }
        if (kc == 0) {
            bias0 = bA_ih[0*H_+j] + bA_hh[0*H_+j];
            bias1 = bA_ih[1*H_+j] + bA_hh[1*H_+j];
            bias2 = bA_ih[2*H_+j] + bA_hh[2*H_+j];
            bias3 = bA_ih[3*H_+j] + bA_hh[3*H_+j];
            w00 = wA_ih[0*H_+j]; w01 = wA_ih[1*H_+j];
            w02 = wA_ih[2*H_+j]; w03 = wA_ih[3*H_+j];
        }
    }
    #pragma unroll
    for (int r = 0; r < 4; ++r)
        #pragma unroll
        for (int q = 0; q < 4; ++q)
            asm volatile("" : "+v"(wt[r][q]));

    float c_st = 0.f;
    float xt = (!isB) ? xA[(long)b * T_] : 0.f;

    if (isB) {
        if (tid < H_) xhB[1][80 + (tid >> 4) * 20 + (tid & 15)] = 0.f;  // h_B[-1]=0
    } else {
        const int t2 = tid - 512;
        if (t2 < H_) xhA[0][(t2 >> 4) * 20 + (t2 & 15)] = 0.f;          // h_A[-1]=0
    }
    block_sync_lds();

    for (int s = 0; s <= T_; ++s) {
        const int rb = s & 1, wb = rb ^ 1;

        if (isB) {
            if (s >= 1) {
                const f32x4* xv = (const f32x4*)&xhB[rb][kc * 20];
                f32x4 h0 = xv[0], h1 = xv[1], h2 = xv[2], h3 = xv[3];
                float acc[4];
                dot4x16(wt, h0, h1, h2, h3, acc);
                acc[0] = dpp_addf<0xB1>(acc[0]); acc[1] = dpp_addf<0xB1>(acc[1]);
                acc[2] = dpp_addf<0xB1>(acc[2]); acc[3] = dpp_addf<0xB1>(acc[3]);
                acc[0] = dpp_addf<0x4E>(acc[0]); acc[1] = dpp_addf<0x4E>(acc[1]);
                acc[2] = dpp_addf<0x4E>(acc[2]); acc[3] = dpp_addf<0x4E>(acc[3]);
                acc[0] = dpp_addf<0x141>(acc[0]); acc[1] = dpp_addf<0x141>(acc[1]);
                acc[2] = dpp_addf<0x141>(acc[2]); acc[3] = dpp_addf<0x141>(acc[3]);
                if (kc == 0) {
                    float i_ = fast_sigmoid(acc[0] + bias0);
                    float f_ = fast_sigmoid(acc[1] + bias1);
                    float g_ = fast_tanh   (acc[2] + bias2);
                    float o_ = fast_sigmoid(acc[3] + bias3);
                    c_st = f_ * c_st + i_ * g_;
                    float h = o_ * fast_tanh(c_st);
                    xhB[wb][80 + (j >> 4) * 20 + (j & 15)] = h;
                    hB_out[((long)b * T_ + (s - 1)) * H_ + j] = h;
                }
            }
        } else {
            if (s < T_) {
                float xn = 0.f;
                if (s + 1 < T_) xn = xA[(long)b * T_ + s + 1];   // wave-uniform
                const f32x4* xv = (const f32x4*)&xhA[rb][kc * 20];
                f32x4 h0 = xv[0], h1 = xv[1], h2 = xv[2], h3 = xv[3];
                float acc[4];
                dot4x16(wt, h0, h1, h2, h3, acc);
                acc[0] = dpp_addf<0xB1>(acc[0]); acc[1] = dpp_addf<0xB1>(acc[1]);
                acc[2] = dpp_addf<0xB1>(acc[2]); acc[3] = dpp_addf<0xB1>(acc[3]);
                acc[0] = dpp_addf<0x4E>(acc[0]); acc[1] = dpp_addf<0x4E>(acc[1]);
                acc[2] = dpp_addf<0x4E>(acc[2]); acc[3] = dpp_addf<0x4E>(acc[3]);
                if (kc == 0) {
                    float gi = acc[0] + bias0 + w00 * xt;
                    float gf = acc[1] + bias1 + w01 * xt;
                    float gg = acc[2] + bias2 + w02 * xt;
                    float go = acc[3] + bias3 + w03 * xt;
                    float i_ = fast_sigmoid(gi);
                    float f_ = fast_sigmoid(gf);
                    float g_ = fast_tanh(gg);
                    float o_ = fast_sigmoid(go);
                    c_st = f_ * c_st + i_ * g_;
                    float h = o_ * fast_tanh(c_st);
                    const int off = (j >> 4) * 20 + (j & 15);
                    xhA[wb][off] = h;
                    xhB[wb][off] = h;                      // feed B's x-slot
                }
                xt = xn;
            }
        }
        block_sync_lds();
    }
}

// ---------------------------------------------------------------------------
// K2: diagonal TRIPLE [L2+L3+L4]. Roles P (L2, t=s), M (L3, t=s-1), Z (L4,
// t=s-2), 256 threads each (NCH=4: thread owns 4 gate rows x 32 k = 128
// weight floats, asm-pinned). Chunks of 32 floats padded to 36 in LDS:
// the 4 distinct b128 addrs hit disjoint bank quads (conflict-free).
// h passes between roles through LDS only; Z writes global (in-place on the
// input buffer; read of row r precedes its overwrite by 3 barrier rounds).
// ---------------------------------------------------------------------------
__global__ __attribute__((amdgpu_flat_work_group_size(768, 768)))
void lstm_triple(const float* xin,    // [B,T,64] h_L1 (aliases hout)
                 float* hout,         // [B,T,64] h_L4
                 const float* __restrict__ wP_ih, const float* __restrict__ wP_hh,
                 const float* __restrict__ bP_ih, const float* __restrict__ bP_hh,
                 const float* __restrict__ wM_ih, const float* __restrict__ wM_hh,
                 const float* __restrict__ bM_ih, const float* __restrict__ bM_hh,
                 const float* __restrict__ wZ_ih, const float* __restrict__ wZ_hh,
                 const float* __restrict__ bZ_ih, const float* __restrict__ bZ_hh)
{
    const int b    = blockIdx.x;
    const int tid  = threadIdx.x;
    const int role = tid >> 8;       // 0=P(L2), 1=M(L3), 2=Z(L4); wave-uniform
    const int loc  = tid & 255;
    const int kc   = loc & 3;        // 32-float chunk of [x|h]
    const int j    = loc >> 2;       // hidden unit

    // per-consumer [x|h] buffers: 4 chunks x 36 floats, double-buffered
    __shared__ __align__(16) float bufP[2][144];
    __shared__ __align__(16) float bufM[2][144];
    __shared__ __align__(16) float bufZ[2][144];

    const float* w_ih = (role == 0) ? wP_ih : (role == 1) ? wM_ih : wZ_ih;
    const float* w_hh = (role == 0) ? wP_hh : (role == 1) ? wM_hh : wZ_hh;
    const float* b_ih = (role == 0) ? bP_ih : (role == 1) ? bM_ih : bZ_ih;
    const float* b_hh = (role == 0) ? bP_hh : (role == 1) ? bM_hh : bZ_hh;
    float (*myBuf)[144] = (role == 0) ? bufP : (role == 1) ? bufM : bufZ;
    float (*dnBuf)[144] = (role == 0) ? bufM : (role == 1) ? bufZ : bufP; // Z's unused

    // ---- weights: 4 rows x 32 k into pinned registers (128 floats) ----
    f32x4 wt[4][8];
    #pragma unroll
    for (int r = 0; r < 4; ++r) {
        const int row = r * H_ + j;
        const float* base = (kc < 2) ? (w_ih + row * H_ + kc * 32)
                                     : (w_hh + row * H_ + (kc - 2) * 32);
        #pragma unroll
        for (int q = 0; q < 8; ++q)
            wt[r][q] = *(const f32x4*)(base + 4 * q);
    }
    #pragma unroll
    for (int r = 0; r < 4; ++r)
        #pragma unroll
        for (int q = 0; q < 8; ++q)
            asm volatile("" : "+v"(wt[r][q]));

    float bias0 = 0.f, bias1 = 0.f, bias2 = 0.f, bias3 = 0.f;
    if (kc == 0) {
        bias0 = b_ih[0*H_+j] + b_hh[0*H_+j];
        bias1 = b_ih[1*H_+j] + b_hh[1*H_+j];
        bias2 = b_ih[2*H_+j] + b_hh[2*H_+j];
        bias3 = b_ih[3*H_+j] + b_hh[3*H_+j];
    }
    float c_st = 0.f;

    // ---- LDS init ----
    // x-slot of unit u: chunk u>>5, elem u&31; h-slot: chunk 2+(u>>5).
    if (tid < 64) {                       // bufP[0]: x = row 0 of xin, h = 0
        const int u = tid;
        bufP[0][(u >> 5) * 36 + (u & 31)] = xin[(long)b * T_ * H_ + u];
        bufP[0][((u >> 5) + 2) * 36 + (u & 31)] = 0.f;
    } else if (tid < 128) {               // bufM[1]: h_L3[-1] = 0
        const int u = tid - 64;
        bufM[1][((u >> 5) + 2) * 36 + (u & 31)] = 0.f;
    } else if (tid < 192) {               // bufZ[0]: h_L4[-1] = 0
        const int u = tid - 128;
        bufZ[0][((u >> 5) + 2) * 36 + (u & 31)] = 0.f;
    }
    block_sync_lds();

    for (int s = 0; s <= T_ + 1; ++s) {
        const int rb = s & 1, wb = rb ^ 1;
        const bool active = (role == 0) ? (s < T_)
                          : (role == 1) ? (s >= 1 && s <= T_)
                                        : (s >= 2);
        if (active) {
            // P: prefetch next x row (kc==1 lanes), hidden behind the matvec
            float xn = 0.f;
            if (role == 0 && kc == 1 && s + 1 < T_)
                xn = xin[((long)b * T_ + s + 1) * H_ + j];

            // ---- ingest chunk kc: 8 conflict-free ds_read_b128 ----
            const f32x4* xv = (const f32x4*)&myBuf[rb][kc * 36];
            f32x4 a0 = {0,0,0,0}, a1 = {0,0,0,0}, a2 = {0,0,0,0}, a3 = {0,0,0,0};
            #pragma unroll
            for (int q = 0; q < 8; ++q) {
                f32x4 hq = xv[q];
                a0 = __builtin_elementwise_fma(wt[0][q], hq, a0);
                a1 = __builtin_elementwise_fma(wt[1][q], hq, a1);
                a2 = __builtin_elementwise_fma(wt[2][q], hq, a2);
                a3 = __builtin_elementwise_fma(wt[3][q], hq, a3);
            }
            float acc0 = hsum4(a0), acc1 = hsum4(a1);
            float acc2 = hsum4(a2), acc3 = hsum4(a3);

            // ---- DPP all-reduce over 4 chunk lanes ----
            acc0 = dpp_addf<0xB1>(acc0); acc1 = dpp_addf<0xB1>(acc1);
            acc2 = dpp_addf<0xB1>(acc2); acc3 = dpp_addf<0xB1>(acc3);
            acc0 = dpp_addf<0x4E>(acc0); acc1 = dpp_addf<0x4E>(acc1);
            acc2 = dpp_addf<0x4E>(acc2); acc3 = dpp_addf<0x4E>(acc3);

            if (kc == 0) {
                float i_ = fast_sigmoid(acc0 + bias0);
                float f_ = fast_sigmoid(acc1 + bias1);
                float g_ = fast_tanh   (acc2 + bias2);
                float o_ = fast_sigmoid(acc3 + bias3);
                c_st = f_ * c_st + i_ * g_;
                float h = o_ * fast_tanh(c_st);
                const int hoff = ((j >> 5) + 2) * 36 + (j & 31);
                const int xoff = (j >> 5) * 36 + (j & 31);
                myBuf[wb][hoff] = h;               // own recurrent h
                if (role < 2) dnBuf[wb][xoff] = h; // feed layer above
                else          hout[((long)b * T_ + (s - 2)) * H_ + j] = h;
            }
            if (role == 0 && kc == 1)
                bufP[wb][(j >> 5) * 36 + (j & 31)] = xn;
        }
        block_sync_lds();
    }
}

// MLP head (R3-R7-validated): wave-uniform W1 -> scalar loads. ~25 us.
__global__ __launch_bounds__(256)
void mlp_head_v2(const float* __restrict__ hbuf,
                 const float* __restrict__ W1,
                 const float* __restrict__ b1,
                 const float* __restrict__ W2,
                 const float* __restrict__ b2,
                 float* __restrict__ out)
{
    const long r = (long)blockIdx.x * 256 + threadIdx.x;

    float row[H_];
    const float4* src = (const float4*)(hbuf + r * H_);
    #pragma unroll
    for (int q = 0; q < 16; ++q) {
        float4 v = src[q];
        row[4*q+0] = fmaxf(v.x, 0.f); row[4*q+1] = fmaxf(v.y, 0.f);
        row[4*q+2] = fmaxf(v.z, 0.f); row[4*q+3] = fmaxf(v.w, 0.f);
    }
    #pragma unroll
    for (int q = 0; q < 16; ++q)
        asm volatile("" : "+v"(row[4*q]), "+v"(row[4*q+1]),
                         "+v"(row[4*q+2]), "+v"(row[4*q+3]));

    float acc = b2[0];
    for (int jj = 0; jj < H_; ++jj) {
        const float* wrow = W1 + jj * H_;
        float s0 = 0.f, s1 = 0.f, s2 = 0.f, s3 = 0.f;
        #pragma unroll
        for (int q = 0; q < 16; ++q) {
            s0 += row[4*q+0] * wrow[4*q+0];
            s1 += row[4*q+1] * wrow[4*q+1];
            s2 += row[4*q+2] * wrow[4*q+2];
            s3 += row[4*q+3] * wrow[4*q+3];
        }
        float y = fmaxf(b1[jj] + (s0 + s1) + (s2 + s3), 0.f);
        acc += y * W2[jj];
    }
    out[r] = acc;
}

extern "C" void kernel_launch(void* const* d_in, const int* in_sizes, int n_in,
                              void* d_out, int out_size, void* d_ws, size_t ws_size,
                              hipStream_t stream) {
    const float* x     = (const float*)d_in[0];   // [B,T,1]
    const float* w_ih0 = (const float*)d_in[1];   // [256]
    const float* w_ihr = (const float*)d_in[2];   // [4,256,64]
    const float* w_hh  = (const float*)d_in[3];   // [5,256,64]
    const float* b_ih  = (const float*)d_in[4];   // [5,256]
    const float* b_hh  = (const float*)d_in[5];   // [5,256]
    const float* W1    = (const float*)d_in[6];   // [64,64]
    const float* b1    = (const float*)d_in[7];   // [64]
    const float* W2    = (const float*)d_in[8];   // [64]
    const float* b2    = (const float*)d_in[9];   // [1]
    // d_in[10] = future (0)

    float* out = (float*)d_out;
    float* buf = (float*)d_ws;                    // [B,T,64] fp32 = 64 MB

    const long LW = 4L * H_ * H_;   // 16384 floats per layer weight block
    const long LB = 4L * H_;        // 256 floats per layer bias block

    // K1: [L0 + L1] diagonal pair -> buf = h_L1
    lstm_pair01<<<dim3(B_), dim3(768), 0, stream>>>(
        x, buf,
        w_ih0,          w_hh + 0 * LW, b_ih + 0 * LB, b_hh + 0 * LB,
        w_ihr + 0 * LW, w_hh + 1 * LW, b_ih + 1 * LB, b_hh + 1 * LB);

    // K2: [L2 + L3 + L4] diagonal triple, in-place on buf -> buf = h_L4
    lstm_triple<<<dim3(B_), dim3(768), 0, stream>>>(
        buf, buf,
        w_ihr + 1 * LW, w_hh + 2 * LW, b_ih + 2 * LB, b_hh + 2 * LB,
        w_ihr + 2 * LW, w_hh + 3 * LW, b_ih + 3 * LB, b_hh + 3 * LB,
        w_ihr + 3 * LW, w_hh + 4 * LW, b_ih + 4 * LB, b_hh + 4 * LB);

    mlp_head_v2<<<dim3((B_ * T_) / 256), dim3(256), 0, stream>>>(
        buf, W1, b1, W2, b2, out);
}